// Round 8
// baseline (234.407 us; speedup 1.0000x reference)
//
#include <hip/hip_runtime.h>

#define NEG_SLOPE 0.2f

typedef __attribute__((ext_vector_type(8))) short short8;
typedef __attribute__((ext_vector_type(4))) float floatx4;

__device__ __forceinline__ unsigned f2bf(float x) {
  unsigned u = __float_as_uint(x);
  unsigned r = ((u >> 16) & 1u) + 0x7fffu;
  return (u + r) >> 16;
}
__device__ __forceinline__ float bf2f(unsigned hi16) {
  return __uint_as_float(hi16 << 16);
}

// ---------------- one-shot: W -> MFMA B-fragments (hi/lo) in global ----------------
// entry u = (ct*4+kc)*64 + lane ; element j: B[k=kc*32+(lane>>4)*8+j][n=ct*16+(lane&15)]
__global__ __launch_bounds__(256) void k_prep(const float* __restrict__ W,
                                              uint4* __restrict__ gWf) {
  const int u = blockIdx.x * 256 + threadIdx.x;
  if (u >= 2048) return;
  int ln = u & 63;
  int kc = (u >> 6) & 3;
  int ct = u >> 8;
  int n = ct * 16 + (ln & 15);
  int kb = kc * 32 + (ln >> 4) * 8;
  int head = n >> 5;
  const float* src = W + head * 4096 + (size_t)kb * 32 + (n & 31);
  unsigned hi[4], lo[4];
#pragma unroll
  for (int jj = 0; jj < 4; ++jj) {
    float w0 = src[(2 * jj) * 32];
    float w1 = src[(2 * jj + 1) * 32];
    unsigned h0 = f2bf(w0), h1 = f2bf(w1);
    unsigned l0 = f2bf(w0 - bf2f(h0)), l1 = f2bf(w1 - bf2f(h1));
    hi[jj] = h0 | (h1 << 16);
    lo[jj] = l0 | (l1 << 16);
  }
  gWf[u] = make_uint4(hi[0], hi[1], hi[2], hi[3]);
  gWf[2048 + u] = make_uint4(lo[0], lo[1], lo[2], lo[3]);
}

// ---------------- pure MFMA projection GEMM + attention dots ----------------
// Split-precision bf16 MFMA: X = Xh + Xl; A*B ~= Ah*Bh + Al*Bh + Ah*Bl.
// Block: 256 thr = 4 waves; 64 rows/block. Direct global A loads (coalesced:
// 4 quads x 32B = 128B contiguous per row).
__global__ __launch_bounds__(256) void k_gemm(const float* __restrict__ h,
                                              const uint4* __restrict__ gWf,
                                              const float* __restrict__ a,
                                              unsigned short* __restrict__ hp16,
                                              float* __restrict__ ssrc,
                                              float* __restrict__ sdst, int N) {
  __shared__ unsigned lds_u[16384];  // 64 KB: B-frags hi [0,8192) lo [8192,16384); reused as epilogue buf
  const int tid = threadIdx.x;
  const int lane = tid & 63;
  const int wv = tid >> 6;
  const int quad = lane >> 4;
  const int l16 = lane & 15;

  // stage precomputed W-fragments: plain 16B/lane copies
  for (int u = tid; u < 4096; u += 256)
    *(uint4*)&lds_u[u * 4] = gWf[u];

  // load A fragments (hi/lo) from global h
  const int row0 = blockIdx.x * 64;
  const int r = row0 + wv * 16 + l16;
  short8 Ah[4], Al[4];
#pragma unroll
  for (int kc = 0; kc < 4; ++kc) {
    float v[8];
    if (r < N) {
      float4 fa = *(const float4*)&h[(size_t)r * 128 + kc * 32 + quad * 8];
      float4 fb = *(const float4*)&h[(size_t)r * 128 + kc * 32 + quad * 8 + 4];
      v[0] = fa.x; v[1] = fa.y; v[2] = fa.z; v[3] = fa.w;
      v[4] = fb.x; v[5] = fb.y; v[6] = fb.z; v[7] = fb.w;
    } else {
#pragma unroll
      for (int j = 0; j < 8; ++j) v[j] = 0.f;
    }
#pragma unroll
    for (int j = 0; j < 8; ++j) {
      unsigned hi = f2bf(v[j]);
      Ah[kc][j] = (short)hi;
      Al[kc][j] = (short)f2bf(v[j] - bf2f(hi));
    }
  }
  __syncthreads();

  // MFMA main: 8 col-tiles x 4 k-chunks x 3 mfma
  floatx4 C[8];
#pragma unroll
  for (int ct = 0; ct < 8; ++ct) {
    floatx4 c = {0.f, 0.f, 0.f, 0.f};
#pragma unroll
    for (int kc = 0; kc < 4; ++kc) {
      int bidx = ((ct * 4 + kc) * 64 + lane) * 4;
      short8 Bh, Bl;
      *(uint4*)&Bh = *(const uint4*)&lds_u[bidx];
      *(uint4*)&Bl = *(const uint4*)&lds_u[8192 + bidx];
      c = __builtin_amdgcn_mfma_f32_16x16x32_bf16(Ah[kc], Bh, c, 0, 0, 0);
      c = __builtin_amdgcn_mfma_f32_16x16x32_bf16(Al[kc], Bh, c, 0, 0, 0);
      c = __builtin_amdgcn_mfma_f32_16x16x32_bf16(Ah[kc], Bl, c, 0, 0, 0);
    }
    C[ct] = c;
  }
  __syncthreads();  // all waves done reading B-frags; reuse LDS as epilogue buf

  // transpose C through LDS (row stride 132 floats)
  float* epi = (float*)lds_u;
#pragma unroll
  for (int ct = 0; ct < 8; ++ct) {
#pragma unroll
    for (int reg = 0; reg < 4; ++reg) {
      int rr = wv * 16 + quad * 4 + reg;
      epi[rr * 132 + ct * 16 + l16] = C[ct][reg];
    }
  }
  __syncthreads();

  // epilogue: 4 threads/row (one per head): a-dots + bf16 pack
  const int row_l = tid >> 2;
  const int hh = tid & 3;
  const int rg = row0 + row_l;
  if (rg < N) {
    const float* rowp = &epi[row_l * 132 + hh * 32];
    float ss = 0.f, sd = 0.f;
    unsigned pka[16];
#pragma unroll
    for (int e = 0; e < 8; ++e) {
      float4 c4 = *(const float4*)&rowp[e * 4];
      float4 as = *(const float4*)&a[hh * 64 + e * 4];
      float4 ad = *(const float4*)&a[hh * 64 + 32 + e * 4];
      ss += c4.x * as.x + c4.y * as.y + c4.z * as.z + c4.w * as.w;
      sd += c4.x * ad.x + c4.y * ad.y + c4.z * ad.z + c4.w * ad.w;
      pka[e * 2] = f2bf(c4.x) | (f2bf(c4.y) << 16);
      pka[e * 2 + 1] = f2bf(c4.z) | (f2bf(c4.w) << 16);
    }
    unsigned short* dst = &hp16[(size_t)rg * 128 + hh * 32];
    *(uint4*)(dst) = make_uint4(pka[0], pka[1], pka[2], pka[3]);
    *(uint4*)(dst + 8) = make_uint4(pka[4], pka[5], pka[6], pka[7]);
    *(uint4*)(dst + 16) = make_uint4(pka[8], pka[9], pka[10], pka[11]);
    *(uint4*)(dst + 24) = make_uint4(pka[12], pka[13], pka[14], pka[15]);
    ssrc[(size_t)rg * 4 + hh] = ss;
    sdst[(size_t)rg * 4 + hh] = sd;
  }
}

// ---------------- sort pass 0: per-block bucket counts (atomic-free global) ----------------
__global__ __launch_bounds__(256) void k_count(const int* __restrict__ ei,
                                               int* __restrict__ gcnt, int E, int NB2) {
  __shared__ int cnt[256];
  const int tid = threadIdx.x;
  const int e0 = blockIdx.x * 4096;
  for (int i = tid; i < NB2; i += 256) cnt[i] = 0;
  __syncthreads();
#pragma unroll
  for (int j = 0; j < 16; ++j) {
    int e = e0 + j * 256 + tid;
    if (e < E) atomicAdd(&cnt[ei[E + e] >> 8], 1);
  }
  __syncthreads();
  for (int i = tid; i < NB2; i += 256) gcnt[blockIdx.x * NB2 + i] = cnt[i];
}

// ---------------- sort pass 1: global scan -> absolute (block,bucket) bases ----------------
// single block; thread t owns bucket t. gcnt becomes absolute base per (block,bucket).
__global__ __launch_bounds__(256) void k_scanall(int* __restrict__ gcnt,
                                                 int* __restrict__ bbase,
                                                 int NB1, int NB2, int E) {
  __shared__ int lds[256];
  const int tid = threadIdx.x;
  int run = 0;
  if (tid < NB2) {
    for (int blk = 0; blk < NB1; ++blk) {
      int c = gcnt[blk * NB2 + tid];
      gcnt[blk * NB2 + tid] = run;
      run += c;
    }
  }
  lds[tid] = (tid < NB2) ? run : 0;
  __syncthreads();
  for (int off = 1; off < 256; off <<= 1) {
    int t = (tid >= off) ? lds[tid - off] : 0;
    __syncthreads();
    lds[tid] += t;
    __syncthreads();
  }
  if (tid < NB2) {
    int excl = lds[tid] - run;
    bbase[tid] = excl;
    if (tid == NB2 - 1) bbase[NB2] = E;
    for (int blk = 0; blk < NB1; ++blk) gcnt[blk * NB2 + tid] += excl;
  }
}

// ---------------- sort pass 2: bin edges, coalesced pair writes, no atomics ----------------
__global__ __launch_bounds__(256) void k_bin(const int* __restrict__ ei,
                                             const int* __restrict__ gcnt,
                                             uint2* __restrict__ gpairs, int E, int NB2) {
  __shared__ uint2 stage[4096];  // 32 KB
  __shared__ int cnt[256], start[256], cur[256], gbase[256];
  const int tid = threadIdx.x;
  const int e0 = blockIdx.x * 4096;
  for (int i = tid; i < NB2; i += 256) cnt[i] = 0;
  __syncthreads();
  int sarr[16], darr[16];
#pragma unroll
  for (int j = 0; j < 16; ++j) {
    int e = e0 + j * 256 + tid;
    if (e < E) {
      sarr[j] = ei[e];
      darr[j] = ei[E + e];
      atomicAdd(&cnt[darr[j] >> 8], 1);
    } else {
      darr[j] = -1;
    }
  }
  __syncthreads();
  {
    int s = (tid < NB2) ? cnt[tid] : 0;
    __shared__ int lds[256];
    lds[tid] = s;
    __syncthreads();
    for (int off = 1; off < 256; off <<= 1) {
      int t = (tid >= off) ? lds[tid - off] : 0;
      __syncthreads();
      lds[tid] += t;
      __syncthreads();
    }
    if (tid < NB2) {
      start[tid] = lds[tid] - s;
      cur[tid] = lds[tid] - s;
      gbase[tid] = gcnt[blockIdx.x * NB2 + tid];
    }
  }
  __syncthreads();
#pragma unroll
  for (int j = 0; j < 16; ++j) {
    if (darr[j] >= 0) {
      int b = darr[j] >> 8;
      int pos = atomicAdd(&cur[b], 1);
      stage[pos] = make_uint2((unsigned)sarr[j], (unsigned)darr[j]);
    }
  }
  __syncthreads();
  const int total = start[NB2 - 1] + cnt[NB2 - 1];
  for (int u = tid; u < total; u += 256) {
    uint2 pr = stage[u];
    int b = (int)(pr.y >> 8);
    gpairs[gbase[b] + (u - start[b])] = pr;
  }
}

// ---------------- sort pass 3: per-bucket counting sort by local dst -> CSR + offs ----------------
__global__ __launch_bounds__(256) void k_build(const int* __restrict__ bbase,
                                               const uint2* __restrict__ gpairs,
                                               int* __restrict__ csr_src,
                                               int* __restrict__ offs, int N) {
  __shared__ int cnt2[256], start2[256], cur2[256];
  __shared__ int srcsort[8192];  // 32 KB; bucket mean ~4096, safe cap
  const int tid = threadIdx.x;
  const int b = blockIdx.x;
  const int base = bbase[b];
  const int size = bbase[b + 1] - base;
  const int d0 = b << 8;
  const int ndst = min(256, N - d0);
  cnt2[tid] = 0;
  __syncthreads();
  for (int u = tid; u < size; u += 256)
    atomicAdd(&cnt2[(int)gpairs[base + u].y - d0], 1);
  __syncthreads();
  {
    int s = cnt2[tid];
    __shared__ int lds[256];
    lds[tid] = s;
    __syncthreads();
    for (int off = 1; off < 256; off <<= 1) {
      int t = (tid >= off) ? lds[tid - off] : 0;
      __syncthreads();
      lds[tid] += t;
      __syncthreads();
    }
    start2[tid] = lds[tid] - s;
    cur2[tid] = lds[tid] - s;
  }
  __syncthreads();
  for (int u = tid; u < size; u += 256) {
    uint2 pr = gpairs[base + u];
    int pos = atomicAdd(&cur2[(int)pr.y - d0], 1);
    srcsort[pos] = (int)pr.x;
  }
  __syncthreads();
  for (int u = tid; u < size; u += 256) csr_src[base + u] = srcsort[u];
  if (tid < ndst) offs[d0 + tid] = base + start2[tid] + cnt2[tid];  // inclusive end
}

// ---------------- aggregation: 16 lanes per dst, 8 ch/lane, single pass ----------------
__global__ __launch_bounds__(256) void k_agg(const int* __restrict__ offs,
                                             const int* __restrict__ csr_src,
                                             const float* __restrict__ ssrc,
                                             const float* __restrict__ sdst,
                                             const uint4* __restrict__ hp4,
                                             float* __restrict__ out, int N) {
  const int t = blockIdx.x * 256 + threadIdx.x;
  const int d = t >> 4;
  if (d >= N) return;
  const int l = threadIdx.x & 15;
  const int hh = l >> 2;
  const int beg = (d == 0) ? 0 : offs[d - 1];
  const int end = offs[d];
  const float sdh = sdst[(size_t)d * 4 + hh];

  float den0 = 0.f, den1 = 0.f;
  float acc[8];
#pragma unroll
  for (int j = 0; j < 8; ++j) acc[j] = 0.f;

  int p = beg;
  for (; p + 1 < end; p += 2) {
    int s0 = csr_src[p];
    int s1 = csr_src[p + 1];
    float sc0 = ssrc[(size_t)s0 * 4 + hh] + sdh;
    float sc1 = ssrc[(size_t)s1 * 4 + hh] + sdh;
    uint4 v0 = hp4[(size_t)s0 * 16 + l];
    uint4 v1 = hp4[(size_t)s1 * 16 + l];
    sc0 = sc0 >= 0.f ? sc0 : NEG_SLOPE * sc0;
    sc1 = sc1 >= 0.f ? sc1 : NEG_SLOPE * sc1;
    float w0 = __expf(sc0);
    float w1 = __expf(sc1);
    den0 += w0;
    den1 += w1;
    acc[0] = fmaf(w0, bf2f(v0.x & 0xffffu), acc[0]);
    acc[1] = fmaf(w0, bf2f(v0.x >> 16), acc[1]);
    acc[2] = fmaf(w0, bf2f(v0.y & 0xffffu), acc[2]);
    acc[3] = fmaf(w0, bf2f(v0.y >> 16), acc[3]);
    acc[4] = fmaf(w0, bf2f(v0.z & 0xffffu), acc[4]);
    acc[5] = fmaf(w0, bf2f(v0.z >> 16), acc[5]);
    acc[6] = fmaf(w0, bf2f(v0.w & 0xffffu), acc[6]);
    acc[7] = fmaf(w0, bf2f(v0.w >> 16), acc[7]);
    acc[0] = fmaf(w1, bf2f(v1.x & 0xffffu), acc[0]);
    acc[1] = fmaf(w1, bf2f(v1.x >> 16), acc[1]);
    acc[2] = fmaf(w1, bf2f(v1.y & 0xffffu), acc[2]);
    acc[3] = fmaf(w1, bf2f(v1.y >> 16), acc[3]);
    acc[4] = fmaf(w1, bf2f(v1.z & 0xffffu), acc[4]);
    acc[5] = fmaf(w1, bf2f(v1.z >> 16), acc[5]);
    acc[6] = fmaf(w1, bf2f(v1.w & 0xffffu), acc[6]);
    acc[7] = fmaf(w1, bf2f(v1.w >> 16), acc[7]);
  }
  if (p < end) {
    int s0 = csr_src[p];
    float sc0 = ssrc[(size_t)s0 * 4 + hh] + sdh;
    uint4 v0 = hp4[(size_t)s0 * 16 + l];
    sc0 = sc0 >= 0.f ? sc0 : NEG_SLOPE * sc0;
    float w0 = __expf(sc0);
    den0 += w0;
    acc[0] = fmaf(w0, bf2f(v0.x & 0xffffu), acc[0]);
    acc[1] = fmaf(w0, bf2f(v0.x >> 16), acc[1]);
    acc[2] = fmaf(w0, bf2f(v0.y & 0xffffu), acc[2]);
    acc[3] = fmaf(w0, bf2f(v0.y >> 16), acc[3]);
    acc[4] = fmaf(w0, bf2f(v0.z & 0xffffu), acc[4]);
    acc[5] = fmaf(w0, bf2f(v0.z >> 16), acc[5]);
    acc[6] = fmaf(w0, bf2f(v0.w & 0xffffu), acc[6]);
    acc[7] = fmaf(w0, bf2f(v0.w >> 16), acc[7]);
  }
  float rden = 1.f / fmaxf(den0 + den1, 1e-16f);
  float o[8];
#pragma unroll
  for (int j = 0; j < 8; ++j) {
    float x = acc[j] * rden;
    o[j] = x > 0.f ? x : expm1f(x);
  }
  float* dst = &out[(size_t)d * 128 + l * 8];
  *(float4*)dst = make_float4(o[0], o[1], o[2], o[3]);
  *(float4*)(dst + 4) = make_float4(o[4], o[5], o[6], o[7]);
}

extern "C" void kernel_launch(void* const* d_in, const int* in_sizes, int n_in,
                              void* d_out, int out_size, void* d_ws, size_t ws_size,
                              hipStream_t stream) {
  const float* h = (const float*)d_in[0];
  const int* ei = (const int*)d_in[1];
  const float* W = (const float*)d_in[2];
  const float* a = (const float*)d_in[3];
  float* out = (float*)d_out;
  const int N = in_sizes[0] / 128;
  const int E = in_sizes[1] / 2;
  const int NB2 = (N + 255) >> 8;          // coarse buckets (dst>>8), <=256
  const int NB1 = (E + 4095) / 4096;       // bin blocks

  char* ws = (char*)d_ws;
  uint4* gWf = (uint4*)ws;                               // 4096 (64 KB)
  unsigned short* hp16 = (unsigned short*)(gWf + 4096);  // N*128 bf16
  uint2* gpairs = (uint2*)(hp16 + (size_t)N * 128);      // E pairs
  float* ssrc = (float*)(gpairs + (size_t)E);            // N*4
  float* sdst = ssrc + (size_t)N * 4;                    // N*4
  int* gcnt = (int*)(sdst + (size_t)N * 4);              // NB1*NB2
  int* bbase = gcnt + (size_t)NB1 * NB2;                 // NB2+1
  int* offs = bbase + NB2 + 1;                           // N
  int* csr_src = offs + N;                               // E

  k_prep<<<8, 256, 0, stream>>>(W, gWf);
  k_gemm<<<(N + 63) / 64, 256, 0, stream>>>(h, gWf, a, hp16, ssrc, sdst, N);
  k_count<<<NB1, 256, 0, stream>>>(ei, gcnt, E, NB2);
  k_scanall<<<1, 256, 0, stream>>>(gcnt, bbase, NB1, NB2, E);
  k_bin<<<NB1, 256, 0, stream>>>(ei, gcnt, gpairs, E, NB2);
  k_build<<<NB2, 256, 0, stream>>>(bbase, gpairs, csr_src, offs, N);
  k_agg<<<(N * 16 + 255) / 256, 256, 0, stream>>>(offs, csr_src, ssrc, sdst,
                                                  (const uint4*)hp16, out, N);
}

// Round 9
// 167.303 us; speedup vs baseline: 1.4011x; 1.4011x over previous
//
#include <hip/hip_runtime.h>

#define NEG_SLOPE 0.2f

typedef __attribute__((ext_vector_type(8))) short short8;
typedef __attribute__((ext_vector_type(4))) float floatx4;

__device__ __forceinline__ unsigned f2bf(float x) {
  unsigned u = __float_as_uint(x);
  unsigned r = ((u >> 16) & 1u) + 0x7fffu;
  return (u + r) >> 16;
}
__device__ __forceinline__ float bf2f(unsigned hi16) {
  return __uint_as_float(hi16 << 16);
}

// ---------------- one-shot: W -> MFMA B-fragments (hi/lo) in global ----------------
__global__ __launch_bounds__(256) void k_prep(const float* __restrict__ W,
                                              uint4* __restrict__ gWf) {
  const int u = blockIdx.x * 256 + threadIdx.x;
  if (u >= 2048) return;
  int ln = u & 63;
  int kc = (u >> 6) & 3;
  int ct = u >> 8;
  int n = ct * 16 + (ln & 15);
  int kb = kc * 32 + (ln >> 4) * 8;
  int head = n >> 5;
  const float* src = W + head * 4096 + (size_t)kb * 32 + (n & 31);
  unsigned hi[4], lo[4];
#pragma unroll
  for (int jj = 0; jj < 4; ++jj) {
    float w0 = src[(2 * jj) * 32];
    float w1 = src[(2 * jj + 1) * 32];
    unsigned h0 = f2bf(w0), h1 = f2bf(w1);
    unsigned l0 = f2bf(w0 - bf2f(h0)), l1 = f2bf(w1 - bf2f(h1));
    hi[jj] = h0 | (h1 << 16);
    lo[jj] = l0 | (l1 << 16);
  }
  gWf[u] = make_uint4(hi[0], hi[1], hi[2], hi[3]);
  gWf[2048 + u] = make_uint4(lo[0], lo[1], lo[2], lo[3]);
}

// ---------------- pure MFMA projection GEMM + attention dots ----------------
__global__ __launch_bounds__(256) void k_gemm(const float* __restrict__ h,
                                              const uint4* __restrict__ gWf,
                                              const float* __restrict__ a,
                                              unsigned short* __restrict__ hp16,
                                              float* __restrict__ ssrc,
                                              float* __restrict__ sdst, int N) {
  __shared__ unsigned lds_u[16384];  // 64 KB: B-frags hi/lo; reused as epilogue buf
  const int tid = threadIdx.x;
  const int lane = tid & 63;
  const int wv = tid >> 6;
  const int quad = lane >> 4;
  const int l16 = lane & 15;

  for (int u = tid; u < 4096; u += 256)
    *(uint4*)&lds_u[u * 4] = gWf[u];

  const int row0 = blockIdx.x * 64;
  const int r = row0 + wv * 16 + l16;
  short8 Ah[4], Al[4];
#pragma unroll
  for (int kc = 0; kc < 4; ++kc) {
    float v[8];
    if (r < N) {
      float4 fa = *(const float4*)&h[(size_t)r * 128 + kc * 32 + quad * 8];
      float4 fb = *(const float4*)&h[(size_t)r * 128 + kc * 32 + quad * 8 + 4];
      v[0] = fa.x; v[1] = fa.y; v[2] = fa.z; v[3] = fa.w;
      v[4] = fb.x; v[5] = fb.y; v[6] = fb.z; v[7] = fb.w;
    } else {
#pragma unroll
      for (int j = 0; j < 8; ++j) v[j] = 0.f;
    }
#pragma unroll
    for (int j = 0; j < 8; ++j) {
      unsigned hi = f2bf(v[j]);
      Ah[kc][j] = (short)hi;
      Al[kc][j] = (short)f2bf(v[j] - bf2f(hi));
    }
  }
  __syncthreads();

  floatx4 C[8];
#pragma unroll
  for (int ct = 0; ct < 8; ++ct) {
    floatx4 c = {0.f, 0.f, 0.f, 0.f};
#pragma unroll
    for (int kc = 0; kc < 4; ++kc) {
      int bidx = ((ct * 4 + kc) * 64 + lane) * 4;
      short8 Bh, Bl;
      *(uint4*)&Bh = *(const uint4*)&lds_u[bidx];
      *(uint4*)&Bl = *(const uint4*)&lds_u[8192 + bidx];
      c = __builtin_amdgcn_mfma_f32_16x16x32_bf16(Ah[kc], Bh, c, 0, 0, 0);
      c = __builtin_amdgcn_mfma_f32_16x16x32_bf16(Al[kc], Bh, c, 0, 0, 0);
      c = __builtin_amdgcn_mfma_f32_16x16x32_bf16(Ah[kc], Bl, c, 0, 0, 0);
    }
    C[ct] = c;
  }
  __syncthreads();

  float* epi = (float*)lds_u;
#pragma unroll
  for (int ct = 0; ct < 8; ++ct) {
#pragma unroll
    for (int reg = 0; reg < 4; ++reg) {
      int rr = wv * 16 + quad * 4 + reg;
      epi[rr * 132 + ct * 16 + l16] = C[ct][reg];
    }
  }
  __syncthreads();

  const int row_l = tid >> 2;
  const int hh = tid & 3;
  const int rg = row0 + row_l;
  if (rg < N) {
    const float* rowp = &epi[row_l * 132 + hh * 32];
    float ss = 0.f, sd = 0.f;
    unsigned pka[16];
#pragma unroll
    for (int e = 0; e < 8; ++e) {
      float4 c4 = *(const float4*)&rowp[e * 4];
      float4 as = *(const float4*)&a[hh * 64 + e * 4];
      float4 ad = *(const float4*)&a[hh * 64 + 32 + e * 4];
      ss += c4.x * as.x + c4.y * as.y + c4.z * as.z + c4.w * as.w;
      sd += c4.x * ad.x + c4.y * ad.y + c4.z * ad.z + c4.w * ad.w;
      pka[e * 2] = f2bf(c4.x) | (f2bf(c4.y) << 16);
      pka[e * 2 + 1] = f2bf(c4.z) | (f2bf(c4.w) << 16);
    }
    unsigned short* dst = &hp16[(size_t)rg * 128 + hh * 32];
    *(uint4*)(dst) = make_uint4(pka[0], pka[1], pka[2], pka[3]);
    *(uint4*)(dst + 8) = make_uint4(pka[4], pka[5], pka[6], pka[7]);
    *(uint4*)(dst + 16) = make_uint4(pka[8], pka[9], pka[10], pka[11]);
    *(uint4*)(dst + 24) = make_uint4(pka[12], pka[13], pka[14], pka[15]);
    ssrc[(size_t)rg * 4 + hh] = ss;
    sdst[(size_t)rg * 4 + hh] = sd;
  }
}

// ---------------- sort pass 0: per-block bucket counts -> transposed matrix ----------------
// gcntT[bucket * NB1 + block]: bucket-major so each bucket's column is contiguous.
__global__ __launch_bounds__(256) void k_count(const int* __restrict__ ei,
                                               int* __restrict__ gcntT,
                                               int E, int NB1, int NB2) {
  __shared__ int cnt[256];
  const int tid = threadIdx.x;
  const int e0 = blockIdx.x * 4096;
  for (int i = tid; i < NB2; i += 256) cnt[i] = 0;
  __syncthreads();
#pragma unroll
  for (int j = 0; j < 16; ++j) {
    int e = e0 + j * 256 + tid;
    if (e < E) atomicAdd(&cnt[ei[E + e] >> 8], 1);
  }
  __syncthreads();
  for (int i = tid; i < NB2; i += 256)
    gcntT[(size_t)i * NB1 + blockIdx.x] = cnt[i];
}

// ---------------- sort pass 1a: per-bucket parallel exclusive scan over blocks ----------------
// one block per bucket; column is contiguous. In-place exclusive; total -> btot.
__global__ __launch_bounds__(256) void k_scan_col(int* __restrict__ gcntT,
                                                  int* __restrict__ btot, int NB1) {
  __shared__ int lds[256];
  const int tid = threadIdx.x;
  int* col = gcntT + (size_t)blockIdx.x * NB1;
  int carry = 0;
  for (int base = 0; base < NB1; base += 256) {
    int i = base + tid;
    int v = (i < NB1) ? col[i] : 0;
    lds[tid] = v;
    __syncthreads();
    for (int off = 1; off < 256; off <<= 1) {
      int t = (tid >= off) ? lds[tid - off] : 0;
      __syncthreads();
      lds[tid] += t;
      __syncthreads();
    }
    if (i < NB1) col[i] = carry + lds[tid] - v;  // exclusive within bucket
    carry += lds[255];
    __syncthreads();
  }
  if (tid == 0) btot[blockIdx.x] = carry;
}

// ---------------- sort pass 1b: scan bucket totals -> bucket bases ----------------
__global__ __launch_bounds__(256) void k_scan_bk(const int* __restrict__ btot,
                                                 int* __restrict__ bbase, int NB2, int E) {
  __shared__ int lds[256];
  const int tid = threadIdx.x;
  int s = (tid < NB2) ? btot[tid] : 0;
  lds[tid] = s;
  __syncthreads();
  for (int off = 1; off < 256; off <<= 1) {
    int t = (tid >= off) ? lds[tid - off] : 0;
    __syncthreads();
    lds[tid] += t;
    __syncthreads();
  }
  if (tid < NB2) {
    bbase[tid] = lds[tid] - s;
    if (tid == NB2 - 1) bbase[NB2] = E;
  }
}

// ---------------- sort pass 2: bin edges, coalesced pair writes ----------------
__global__ __launch_bounds__(256) void k_bin(const int* __restrict__ ei,
                                             const int* __restrict__ gcntT,
                                             const int* __restrict__ bbase,
                                             uint2* __restrict__ gpairs,
                                             int E, int NB1, int NB2) {
  __shared__ uint2 stage[4096];  // 32 KB
  __shared__ int cnt[256], start[256], cur[256], gbase[256];
  const int tid = threadIdx.x;
  const int e0 = blockIdx.x * 4096;
  for (int i = tid; i < NB2; i += 256) cnt[i] = 0;
  __syncthreads();
  int sarr[16], darr[16];
#pragma unroll
  for (int j = 0; j < 16; ++j) {
    int e = e0 + j * 256 + tid;
    if (e < E) {
      sarr[j] = ei[e];
      darr[j] = ei[E + e];
      atomicAdd(&cnt[darr[j] >> 8], 1);
    } else {
      darr[j] = -1;
    }
  }
  __syncthreads();
  {
    int s = (tid < NB2) ? cnt[tid] : 0;
    __shared__ int lds[256];
    lds[tid] = s;
    __syncthreads();
    for (int off = 1; off < 256; off <<= 1) {
      int t = (tid >= off) ? lds[tid - off] : 0;
      __syncthreads();
      lds[tid] += t;
      __syncthreads();
    }
    if (tid < NB2) {
      start[tid] = lds[tid] - s;
      cur[tid] = lds[tid] - s;
      gbase[tid] = gcntT[(size_t)tid * NB1 + blockIdx.x] + bbase[tid];
    }
  }
  __syncthreads();
#pragma unroll
  for (int j = 0; j < 16; ++j) {
    if (darr[j] >= 0) {
      int b = darr[j] >> 8;
      int pos = atomicAdd(&cur[b], 1);
      stage[pos] = make_uint2((unsigned)sarr[j], (unsigned)darr[j]);
    }
  }
  __syncthreads();
  const int total = start[NB2 - 1] + cnt[NB2 - 1];
  for (int u = tid; u < total; u += 256) {
    uint2 pr = stage[u];
    int b = (int)(pr.y >> 8);
    gpairs[gbase[b] + (u - start[b])] = pr;
  }
}

// ---------------- sort pass 3: per-bucket counting sort by local dst -> CSR + offs ----------------
__global__ __launch_bounds__(256) void k_build(const int* __restrict__ bbase,
                                               const uint2* __restrict__ gpairs,
                                               int* __restrict__ csr_src,
                                               int* __restrict__ offs, int N) {
  __shared__ int cnt2[256], start2[256], cur2[256];
  __shared__ int srcsort[8192];  // 32 KB; bucket mean ~4096, safe cap
  const int tid = threadIdx.x;
  const int b = blockIdx.x;
  const int base = bbase[b];
  const int size = bbase[b + 1] - base;
  const int d0 = b << 8;
  const int ndst = min(256, N - d0);
  cnt2[tid] = 0;
  __syncthreads();
  for (int u = tid; u < size; u += 256)
    atomicAdd(&cnt2[(int)gpairs[base + u].y - d0], 1);
  __syncthreads();
  {
    int s = cnt2[tid];
    __shared__ int lds[256];
    lds[tid] = s;
    __syncthreads();
    for (int off = 1; off < 256; off <<= 1) {
      int t = (tid >= off) ? lds[tid - off] : 0;
      __syncthreads();
      lds[tid] += t;
      __syncthreads();
    }
    start2[tid] = lds[tid] - s;
    cur2[tid] = lds[tid] - s;
  }
  __syncthreads();
  for (int u = tid; u < size; u += 256) {
    uint2 pr = gpairs[base + u];
    int pos = atomicAdd(&cur2[(int)pr.y - d0], 1);
    srcsort[pos] = (int)pr.x;
  }
  __syncthreads();
  for (int u = tid; u < size; u += 256) csr_src[base + u] = srcsort[u];
  if (tid < ndst) offs[d0 + tid] = base + start2[tid] + cnt2[tid];  // inclusive end
}

// ---------------- aggregation: 16 lanes per dst, 8 ch/lane, single pass ----------------
__global__ __launch_bounds__(256) void k_agg(const int* __restrict__ offs,
                                             const int* __restrict__ csr_src,
                                             const float* __restrict__ ssrc,
                                             const float* __restrict__ sdst,
                                             const uint4* __restrict__ hp4,
                                             float* __restrict__ out, int N) {
  const int t = blockIdx.x * 256 + threadIdx.x;
  const int d = t >> 4;
  if (d >= N) return;
  const int l = threadIdx.x & 15;
  const int hh = l >> 2;
  const int beg = (d == 0) ? 0 : offs[d - 1];
  const int end = offs[d];
  const float sdh = sdst[(size_t)d * 4 + hh];

  float den0 = 0.f, den1 = 0.f;
  float acc[8];
#pragma unroll
  for (int j = 0; j < 8; ++j) acc[j] = 0.f;

  int p = beg;
  for (; p + 1 < end; p += 2) {
    int s0 = csr_src[p];
    int s1 = csr_src[p + 1];
    float sc0 = ssrc[(size_t)s0 * 4 + hh] + sdh;
    float sc1 = ssrc[(size_t)s1 * 4 + hh] + sdh;
    uint4 v0 = hp4[(size_t)s0 * 16 + l];
    uint4 v1 = hp4[(size_t)s1 * 16 + l];
    sc0 = sc0 >= 0.f ? sc0 : NEG_SLOPE * sc0;
    sc1 = sc1 >= 0.f ? sc1 : NEG_SLOPE * sc1;
    float w0 = __expf(sc0);
    float w1 = __expf(sc1);
    den0 += w0;
    den1 += w1;
    acc[0] = fmaf(w0, bf2f(v0.x & 0xffffu), acc[0]);
    acc[1] = fmaf(w0, bf2f(v0.x >> 16), acc[1]);
    acc[2] = fmaf(w0, bf2f(v0.y & 0xffffu), acc[2]);
    acc[3] = fmaf(w0, bf2f(v0.y >> 16), acc[3]);
    acc[4] = fmaf(w0, bf2f(v0.z & 0xffffu), acc[4]);
    acc[5] = fmaf(w0, bf2f(v0.z >> 16), acc[5]);
    acc[6] = fmaf(w0, bf2f(v0.w & 0xffffu), acc[6]);
    acc[7] = fmaf(w0, bf2f(v0.w >> 16), acc[7]);
    acc[0] = fmaf(w1, bf2f(v1.x & 0xffffu), acc[0]);
    acc[1] = fmaf(w1, bf2f(v1.x >> 16), acc[1]);
    acc[2] = fmaf(w1, bf2f(v1.y & 0xffffu), acc[2]);
    acc[3] = fmaf(w1, bf2f(v1.y >> 16), acc[3]);
    acc[4] = fmaf(w1, bf2f(v1.z & 0xffffu), acc[4]);
    acc[5] = fmaf(w1, bf2f(v1.z >> 16), acc[5]);
    acc[6] = fmaf(w1, bf2f(v1.w & 0xffffu), acc[6]);
    acc[7] = fmaf(w1, bf2f(v1.w >> 16), acc[7]);
  }
  if (p < end) {
    int s0 = csr_src[p];
    float sc0 = ssrc[(size_t)s0 * 4 + hh] + sdh;
    uint4 v0 = hp4[(size_t)s0 * 16 + l];
    sc0 = sc0 >= 0.f ? sc0 : NEG_SLOPE * sc0;
    float w0 = __expf(sc0);
    den0 += w0;
    acc[0] = fmaf(w0, bf2f(v0.x & 0xffffu), acc[0]);
    acc[1] = fmaf(w0, bf2f(v0.x >> 16), acc[1]);
    acc[2] = fmaf(w0, bf2f(v0.y & 0xffffu), acc[2]);
    acc[3] = fmaf(w0, bf2f(v0.y >> 16), acc[3]);
    acc[4] = fmaf(w0, bf2f(v0.z & 0xffffu), acc[4]);
    acc[5] = fmaf(w0, bf2f(v0.z >> 16), acc[5]);
    acc[6] = fmaf(w0, bf2f(v0.w & 0xffffu), acc[6]);
    acc[7] = fmaf(w0, bf2f(v0.w >> 16), acc[7]);
  }
  float rden = 1.f / fmaxf(den0 + den1, 1e-16f);
  float o[8];
#pragma unroll
  for (int j = 0; j < 8; ++j) {
    float x = acc[j] * rden;
    o[j] = x > 0.f ? x : expm1f(x);
  }
  float* dst = &out[(size_t)d * 128 + l * 8];
  *(float4*)dst = make_float4(o[0], o[1], o[2], o[3]);
  *(float4*)(dst + 4) = make_float4(o[4], o[5], o[6], o[7]);
}

extern "C" void kernel_launch(void* const* d_in, const int* in_sizes, int n_in,
                              void* d_out, int out_size, void* d_ws, size_t ws_size,
                              hipStream_t stream) {
  const float* h = (const float*)d_in[0];
  const int* ei = (const int*)d_in[1];
  const float* W = (const float*)d_in[2];
  const float* a = (const float*)d_in[3];
  float* out = (float*)d_out;
  const int N = in_sizes[0] / 128;
  const int E = in_sizes[1] / 2;
  const int NB2 = (N + 255) >> 8;          // coarse buckets (dst>>8), <=256
  const int NB1 = (E + 4095) / 4096;       // bin blocks

  char* ws = (char*)d_ws;
  uint4* gWf = (uint4*)ws;                               // 4096 (64 KB)
  unsigned short* hp16 = (unsigned short*)(gWf + 4096);  // N*128 bf16
  uint2* gpairs = (uint2*)(hp16 + (size_t)N * 128);      // E pairs
  float* ssrc = (float*)(gpairs + (size_t)E);            // N*4
  float* sdst = ssrc + (size_t)N * 4;                    // N*4
  int* gcntT = (int*)(sdst + (size_t)N * 4);             // NB2*NB1 (bucket-major)
  int* btot = gcntT + (size_t)NB2 * NB1;                 // NB2
  int* bbase = btot + NB2;                               // NB2+1
  int* offs = bbase + NB2 + 1;                           // N
  int* csr_src = offs + N;                               // E

  k_prep<<<8, 256, 0, stream>>>(W, gWf);
  k_gemm<<<(N + 63) / 64, 256, 0, stream>>>(h, gWf, a, hp16, ssrc, sdst, N);
  k_count<<<NB1, 256, 0, stream>>>(ei, gcntT, E, NB1, NB2);
  k_scan_col<<<NB2, 256, 0, stream>>>(gcntT, btot, NB1);
  k_scan_bk<<<1, 256, 0, stream>>>(btot, bbase, NB2, E);
  k_bin<<<NB1, 256, 0, stream>>>(ei, gcntT, bbase, gpairs, E, NB1, NB2);
  k_build<<<NB2, 256, 0, stream>>>(bbase, gpairs, csr_src, offs, N);
  k_agg<<<(N * 16 + 255) / 256, 256, 0, stream>>>(offs, csr_src, ssrc, sdst,
                                                  (const uint4*)hp16, out, N);
}

// Round 10
// 163.628 us; speedup vs baseline: 1.4326x; 1.0225x over previous
//
#include <hip/hip_runtime.h>

#define NEG_SLOPE 0.2f

typedef __attribute__((ext_vector_type(8))) short short8;
typedef __attribute__((ext_vector_type(4))) float floatx4;

__device__ __forceinline__ unsigned f2bf(float x) {
  unsigned u = __float_as_uint(x);
  unsigned r = ((u >> 16) & 1u) + 0x7fffu;
  return (u + r) >> 16;
}
__device__ __forceinline__ float bf2f(unsigned hi16) {
  return __uint_as_float(hi16 << 16);
}

// ---------------- one-shot: W -> MFMA B-fragments (hi/lo) in global ----------------
__global__ __launch_bounds__(256) void k_prep(const float* __restrict__ W,
                                              uint4* __restrict__ gWf) {
  const int u = blockIdx.x * 256 + threadIdx.x;
  if (u >= 2048) return;
  int ln = u & 63;
  int kc = (u >> 6) & 3;
  int ct = u >> 8;
  int n = ct * 16 + (ln & 15);
  int kb = kc * 32 + (ln >> 4) * 8;
  int head = n >> 5;
  const float* src = W + head * 4096 + (size_t)kb * 32 + (n & 31);
  unsigned hi[4], lo[4];
#pragma unroll
  for (int jj = 0; jj < 4; ++jj) {
    float w0 = src[(2 * jj) * 32];
    float w1 = src[(2 * jj + 1) * 32];
    unsigned h0 = f2bf(w0), h1 = f2bf(w1);
    unsigned l0 = f2bf(w0 - bf2f(h0)), l1 = f2bf(w1 - bf2f(h1));
    hi[jj] = h0 | (h1 << 16);
    lo[jj] = l0 | (l1 << 16);
  }
  gWf[u] = make_uint4(hi[0], hi[1], hi[2], hi[3]);
  gWf[2048 + u] = make_uint4(lo[0], lo[1], lo[2], lo[3]);
}

// ---------------- fused: MFMA projection GEMM + attention dots + edge count ----------------
// Split-precision bf16 MFMA: X = Xh + Xl; A*B ~= Ah*Bh + Al*Bh + Ah*Bl.
// First NB1 blocks also histogram their edge chunk (independent work, hides
// under GEMM occupancy). gcntT is bucket-major: gcntT[bucket*NB1 + block].
__global__ __launch_bounds__(256) void k_gemm(const float* __restrict__ h,
                                              const uint4* __restrict__ gWf,
                                              const float* __restrict__ a,
                                              const int* __restrict__ ei,
                                              unsigned short* __restrict__ hp16,
                                              float* __restrict__ ssrc,
                                              float* __restrict__ sdst,
                                              int* __restrict__ gcntT,
                                              int N, int E, int NB1, int NB2) {
  __shared__ unsigned lds_u[16384];  // 64 KB: B-frags hi/lo; reused as epilogue buf
  __shared__ int cnt[256];
  const int tid = threadIdx.x;

  if (blockIdx.x < NB1) {  // block-uniform branch: barriers inside are legal
    for (int i = tid; i < NB2; i += 256) cnt[i] = 0;
    __syncthreads();
    const int e0 = blockIdx.x * 4096;
#pragma unroll
    for (int j = 0; j < 16; ++j) {
      int e = e0 + j * 256 + tid;
      if (e < E) atomicAdd(&cnt[ei[E + e] >> 8], 1);
    }
    __syncthreads();
    for (int i = tid; i < NB2; i += 256)
      gcntT[(size_t)i * NB1 + blockIdx.x] = cnt[i];
  }

  const int lane = tid & 63;
  const int wv = tid >> 6;
  const int quad = lane >> 4;
  const int l16 = lane & 15;

  for (int u = tid; u < 4096; u += 256)
    *(uint4*)&lds_u[u * 4] = gWf[u];

  const int row0 = blockIdx.x * 64;
  const int r = row0 + wv * 16 + l16;
  short8 Ah[4], Al[4];
#pragma unroll
  for (int kc = 0; kc < 4; ++kc) {
    float v[8];
    if (r < N) {
      float4 fa = *(const float4*)&h[(size_t)r * 128 + kc * 32 + quad * 8];
      float4 fb = *(const float4*)&h[(size_t)r * 128 + kc * 32 + quad * 8 + 4];
      v[0] = fa.x; v[1] = fa.y; v[2] = fa.z; v[3] = fa.w;
      v[4] = fb.x; v[5] = fb.y; v[6] = fb.z; v[7] = fb.w;
    } else {
#pragma unroll
      for (int j = 0; j < 8; ++j) v[j] = 0.f;
    }
#pragma unroll
    for (int j = 0; j < 8; ++j) {
      unsigned hi = f2bf(v[j]);
      Ah[kc][j] = (short)hi;
      Al[kc][j] = (short)f2bf(v[j] - bf2f(hi));
    }
  }
  __syncthreads();

  floatx4 C[8];
#pragma unroll
  for (int ct = 0; ct < 8; ++ct) {
    floatx4 c = {0.f, 0.f, 0.f, 0.f};
#pragma unroll
    for (int kc = 0; kc < 4; ++kc) {
      int bidx = ((ct * 4 + kc) * 64 + lane) * 4;
      short8 Bh, Bl;
      *(uint4*)&Bh = *(const uint4*)&lds_u[bidx];
      *(uint4*)&Bl = *(const uint4*)&lds_u[8192 + bidx];
      c = __builtin_amdgcn_mfma_f32_16x16x32_bf16(Ah[kc], Bh, c, 0, 0, 0);
      c = __builtin_amdgcn_mfma_f32_16x16x32_bf16(Al[kc], Bh, c, 0, 0, 0);
      c = __builtin_amdgcn_mfma_f32_16x16x32_bf16(Ah[kc], Bl, c, 0, 0, 0);
    }
    C[ct] = c;
  }
  __syncthreads();

  float* epi = (float*)lds_u;
#pragma unroll
  for (int ct = 0; ct < 8; ++ct) {
#pragma unroll
    for (int reg = 0; reg < 4; ++reg) {
      int rr = wv * 16 + quad * 4 + reg;
      epi[rr * 132 + ct * 16 + l16] = C[ct][reg];
    }
  }
  __syncthreads();

  const int row_l = tid >> 2;
  const int hh = tid & 3;
  const int rg = row0 + row_l;
  if (rg < N) {
    const float* rowp = &epi[row_l * 132 + hh * 32];
    float ss = 0.f, sd = 0.f;
    unsigned pka[16];
#pragma unroll
    for (int e = 0; e < 8; ++e) {
      float4 c4 = *(const float4*)&rowp[e * 4];
      float4 as = *(const float4*)&a[hh * 64 + e * 4];
      float4 ad = *(const float4*)&a[hh * 64 + 32 + e * 4];
      ss += c4.x * as.x + c4.y * as.y + c4.z * as.z + c4.w * as.w;
      sd += c4.x * ad.x + c4.y * ad.y + c4.z * ad.z + c4.w * ad.w;
      pka[e * 2] = f2bf(c4.x) | (f2bf(c4.y) << 16);
      pka[e * 2 + 1] = f2bf(c4.z) | (f2bf(c4.w) << 16);
    }
    unsigned short* dst = &hp16[(size_t)rg * 128 + hh * 32];
    *(uint4*)(dst) = make_uint4(pka[0], pka[1], pka[2], pka[3]);
    *(uint4*)(dst + 8) = make_uint4(pka[4], pka[5], pka[6], pka[7]);
    *(uint4*)(dst + 16) = make_uint4(pka[8], pka[9], pka[10], pka[11]);
    *(uint4*)(dst + 24) = make_uint4(pka[12], pka[13], pka[14], pka[15]);
    ssrc[(size_t)rg * 4 + hh] = ss;
    sdst[(size_t)rg * 4 + hh] = sd;
  }
}

// ---------------- sort 1a: per-bucket parallel exclusive scan over blocks ----------------
__global__ __launch_bounds__(256) void k_scan_col(int* __restrict__ gcntT,
                                                  int* __restrict__ btot, int NB1) {
  __shared__ int lds[256];
  const int tid = threadIdx.x;
  int* col = gcntT + (size_t)blockIdx.x * NB1;
  int carry = 0;
  for (int base = 0; base < NB1; base += 256) {
    int i = base + tid;
    int v = (i < NB1) ? col[i] : 0;
    lds[tid] = v;
    __syncthreads();
    for (int off = 1; off < 256; off <<= 1) {
      int t = (tid >= off) ? lds[tid - off] : 0;
      __syncthreads();
      lds[tid] += t;
      __syncthreads();
    }
    if (i < NB1) col[i] = carry + lds[tid] - v;  // exclusive within bucket
    carry += lds[255];
    __syncthreads();
  }
  if (tid == 0) btot[blockIdx.x] = carry;
}

// ---------------- sort 2: bin edges, coalesced pair writes (inline btot scan) ----------------
__global__ __launch_bounds__(256) void k_bin(const int* __restrict__ ei,
                                             const int* __restrict__ gcntT,
                                             const int* __restrict__ btot,
                                             uint2* __restrict__ gpairs,
                                             int E, int NB1, int NB2) {
  __shared__ uint2 stage[4096];  // 32 KB
  __shared__ int cnt[256], start[256], cur[256], gbase[256];
  __shared__ int lds[256];
  const int tid = threadIdx.x;
  const int e0 = blockIdx.x * 4096;
  // bucket bases: exclusive scan of btot, redone per block (cheap, L2-hot)
  int bt = (tid < NB2) ? btot[tid] : 0;
  lds[tid] = bt;
  __syncthreads();
  for (int off = 1; off < 256; off <<= 1) {
    int t = (tid >= off) ? lds[tid - off] : 0;
    __syncthreads();
    lds[tid] += t;
    __syncthreads();
  }
  const int bbase_t = lds[tid] - bt;  // exclusive base of bucket tid
  for (int i = tid; i < NB2; i += 256) cnt[i] = 0;
  __syncthreads();
  int sarr[16], darr[16];
#pragma unroll
  for (int j = 0; j < 16; ++j) {
    int e = e0 + j * 256 + tid;
    if (e < E) {
      sarr[j] = ei[e];
      darr[j] = ei[E + e];
      atomicAdd(&cnt[darr[j] >> 8], 1);
    } else {
      darr[j] = -1;
    }
  }
  __syncthreads();
  {
    int s = (tid < NB2) ? cnt[tid] : 0;
    lds[tid] = s;
    __syncthreads();
    for (int off = 1; off < 256; off <<= 1) {
      int t = (tid >= off) ? lds[tid - off] : 0;
      __syncthreads();
      lds[tid] += t;
      __syncthreads();
    }
    if (tid < NB2) {
      start[tid] = lds[tid] - s;
      cur[tid] = lds[tid] - s;
      gbase[tid] = gcntT[(size_t)tid * NB1 + blockIdx.x] + bbase_t;
    }
  }
  __syncthreads();
#pragma unroll
  for (int j = 0; j < 16; ++j) {
    if (darr[j] >= 0) {
      int b = darr[j] >> 8;
      int pos = atomicAdd(&cur[b], 1);
      stage[pos] = make_uint2((unsigned)sarr[j], (unsigned)darr[j]);
    }
  }
  __syncthreads();
  const int total = start[NB2 - 1] + cnt[NB2 - 1];
  for (int u = tid; u < total; u += 256) {
    uint2 pr = stage[u];
    int b = (int)(pr.y >> 8);
    gpairs[gbase[b] + (u - start[b])] = pr;
  }
}

// ---------------- sort 3: per-bucket counting sort -> CSR + offs (inline btot scan) ----------------
__global__ __launch_bounds__(256) void k_build(const int* __restrict__ btot,
                                               const uint2* __restrict__ gpairs,
                                               int* __restrict__ csr_src,
                                               int* __restrict__ offs, int N, int NB2) {
  __shared__ int cnt2[256], start2[256], cur2[256];
  __shared__ int lds[256];
  __shared__ int bshare[2];
  __shared__ int srcsort[8192];  // 32 KB; bucket mean ~4096, safe cap
  const int tid = threadIdx.x;
  const int b = blockIdx.x;
  // bucket base: exclusive scan of btot
  int bt = (tid < NB2) ? btot[tid] : 0;
  lds[tid] = bt;
  __syncthreads();
  for (int off = 1; off < 256; off <<= 1) {
    int t = (tid >= off) ? lds[tid - off] : 0;
    __syncthreads();
    lds[tid] += t;
    __syncthreads();
  }
  if (tid == b) {
    bshare[0] = lds[tid] - bt;  // base
    bshare[1] = bt;             // size
  }
  cnt2[tid] = 0;
  __syncthreads();
  const int base = bshare[0];
  const int size = bshare[1];
  const int d0 = b << 8;
  const int ndst = min(256, N - d0);
  for (int u = tid; u < size; u += 256)
    atomicAdd(&cnt2[(int)gpairs[base + u].y - d0], 1);
  __syncthreads();
  {
    int s = cnt2[tid];
    lds[tid] = s;
    __syncthreads();
    for (int off = 1; off < 256; off <<= 1) {
      int t = (tid >= off) ? lds[tid - off] : 0;
      __syncthreads();
      lds[tid] += t;
      __syncthreads();
    }
    start2[tid] = lds[tid] - s;
    cur2[tid] = lds[tid] - s;
  }
  __syncthreads();
  for (int u = tid; u < size; u += 256) {
    uint2 pr = gpairs[base + u];
    int pos = atomicAdd(&cur2[(int)pr.y - d0], 1);
    srcsort[pos] = (int)pr.x;
  }
  __syncthreads();
  for (int u = tid; u < size; u += 256) csr_src[base + u] = srcsort[u];
  if (tid < ndst) offs[d0 + tid] = base + start2[tid] + cnt2[tid];  // inclusive end
}

// ---------------- aggregation: 16 lanes per dst, 8 ch/lane, unroll x4 ----------------
__global__ __launch_bounds__(256) void k_agg(const int* __restrict__ offs,
                                             const int* __restrict__ csr_src,
                                             const float* __restrict__ ssrc,
                                             const float* __restrict__ sdst,
                                             const uint4* __restrict__ hp4,
                                             float* __restrict__ out, int N) {
  const int t = blockIdx.x * 256 + threadIdx.x;
  const int d = t >> 4;
  if (d >= N) return;
  const int l = threadIdx.x & 15;
  const int hh = l >> 2;
  const int beg = (d == 0) ? 0 : offs[d - 1];
  const int end = offs[d];
  const float sdh = sdst[(size_t)d * 4 + hh];

  float den[4] = {0.f, 0.f, 0.f, 0.f};
  float acc[8];
#pragma unroll
  for (int j = 0; j < 8; ++j) acc[j] = 0.f;

  int p = beg;
  for (; p + 3 < end; p += 4) {
    int s[4];
    float sc[4];
    uint4 v[4];
#pragma unroll
    for (int q = 0; q < 4; ++q) s[q] = csr_src[p + q];
#pragma unroll
    for (int q = 0; q < 4; ++q) {
      sc[q] = ssrc[(size_t)s[q] * 4 + hh] + sdh;
      v[q] = hp4[(size_t)s[q] * 16 + l];
    }
#pragma unroll
    for (int q = 0; q < 4; ++q) {
      float x = sc[q];
      x = x >= 0.f ? x : NEG_SLOPE * x;
      float w = __expf(x);
      den[q] += w;
      acc[0] = fmaf(w, bf2f(v[q].x & 0xffffu), acc[0]);
      acc[1] = fmaf(w, bf2f(v[q].x >> 16), acc[1]);
      acc[2] = fmaf(w, bf2f(v[q].y & 0xffffu), acc[2]);
      acc[3] = fmaf(w, bf2f(v[q].y >> 16), acc[3]);
      acc[4] = fmaf(w, bf2f(v[q].z & 0xffffu), acc[4]);
      acc[5] = fmaf(w, bf2f(v[q].z >> 16), acc[5]);
      acc[6] = fmaf(w, bf2f(v[q].w & 0xffffu), acc[6]);
      acc[7] = fmaf(w, bf2f(v[q].w >> 16), acc[7]);
    }
  }
  for (; p < end; ++p) {
    int s0 = csr_src[p];
    float sc0 = ssrc[(size_t)s0 * 4 + hh] + sdh;
    uint4 v0 = hp4[(size_t)s0 * 16 + l];
    sc0 = sc0 >= 0.f ? sc0 : NEG_SLOPE * sc0;
    float w0 = __expf(sc0);
    den[0] += w0;
    acc[0] = fmaf(w0, bf2f(v0.x & 0xffffu), acc[0]);
    acc[1] = fmaf(w0, bf2f(v0.x >> 16), acc[1]);
    acc[2] = fmaf(w0, bf2f(v0.y & 0xffffu), acc[2]);
    acc[3] = fmaf(w0, bf2f(v0.y >> 16), acc[3]);
    acc[4] = fmaf(w0, bf2f(v0.z & 0xffffu), acc[4]);
    acc[5] = fmaf(w0, bf2f(v0.z >> 16), acc[5]);
    acc[6] = fmaf(w0, bf2f(v0.w & 0xffffu), acc[6]);
    acc[7] = fmaf(w0, bf2f(v0.w >> 16), acc[7]);
  }
  float rden = 1.f / fmaxf((den[0] + den[1]) + (den[2] + den[3]), 1e-16f);
  float o[8];
#pragma unroll
  for (int j = 0; j < 8; ++j) {
    float x = acc[j] * rden;
    o[j] = x > 0.f ? x : expm1f(x);
  }
  float* dst = &out[(size_t)d * 128 + l * 8];
  *(float4*)dst = make_float4(o[0], o[1], o[2], o[3]);
  *(float4*)(dst + 4) = make_float4(o[4], o[5], o[6], o[7]);
}

extern "C" void kernel_launch(void* const* d_in, const int* in_sizes, int n_in,
                              void* d_out, int out_size, void* d_ws, size_t ws_size,
                              hipStream_t stream) {
  const float* h = (const float*)d_in[0];
  const int* ei = (const int*)d_in[1];
  const float* W = (const float*)d_in[2];
  const float* a = (const float*)d_in[3];
  float* out = (float*)d_out;
  const int N = in_sizes[0] / 128;
  const int E = in_sizes[1] / 2;
  const int NB2 = (N + 255) >> 8;          // coarse buckets (dst>>8), <=256
  const int NB1 = (E + 4095) / 4096;       // edge chunks

  char* ws = (char*)d_ws;
  uint4* gWf = (uint4*)ws;                               // 4096 (64 KB)
  unsigned short* hp16 = (unsigned short*)(gWf + 4096);  // N*128 bf16
  uint2* gpairs = (uint2*)(hp16 + (size_t)N * 128);      // E pairs
  float* ssrc = (float*)(gpairs + (size_t)E);            // N*4
  float* sdst = ssrc + (size_t)N * 4;                    // N*4
  int* gcntT = (int*)(sdst + (size_t)N * 4);             // NB2*NB1 (bucket-major)
  int* btot = gcntT + (size_t)NB2 * NB1;                 // NB2
  int* offs = btot + NB2;                                // N
  int* csr_src = offs + N;                               // E

  k_prep<<<8, 256, 0, stream>>>(W, gWf);
  k_gemm<<<(N + 63) / 64, 256, 0, stream>>>(h, gWf, a, ei, hp16, ssrc, sdst,
                                            gcntT, N, E, NB1, NB2);
  k_scan_col<<<NB2, 256, 0, stream>>>(gcntT, btot, NB1);
  k_bin<<<NB1, 256, 0, stream>>>(ei, gcntT, btot, gpairs, E, NB1, NB2);
  k_build<<<NB2, 256, 0, stream>>>(btot, gpairs, csr_src, offs, N, NB2);
  k_agg<<<(N * 16 + 255) / 256, 256, 0, stream>>>(offs, csr_src, ssrc, sdst,
                                                  (const uint4*)hp16, out, N);
}

// Round 11
// 159.660 us; speedup vs baseline: 1.4682x; 1.0249x over previous
//
#include <hip/hip_runtime.h>

#define NEG_SLOPE 0.2f
#define BCAP 8192  // per-bucket slot capacity (mean 4096, sigma ~64 -> +64 sigma)

typedef __attribute__((ext_vector_type(8))) short short8;
typedef __attribute__((ext_vector_type(4))) float floatx4;

__device__ __forceinline__ unsigned f2bf(float x) {
  unsigned u = __float_as_uint(x);
  unsigned r = ((u >> 16) & 1u) + 0x7fffu;
  return (u + r) >> 16;
}
__device__ __forceinline__ float bf2f(unsigned hi16) {
  return __uint_as_float(hi16 << 16);
}

// ---------------- one-shot: W -> MFMA B-fragments (hi/lo) + zero bucket cursors ----------------
__global__ __launch_bounds__(256) void k_prep(const float* __restrict__ W,
                                              uint4* __restrict__ gWf,
                                              int* __restrict__ bcur, int NB2) {
  if (blockIdx.x == 0 && threadIdx.x < NB2) bcur[threadIdx.x] = 0;
  const int u = blockIdx.x * 256 + threadIdx.x;
  if (u >= 2048) return;
  int ln = u & 63;
  int kc = (u >> 6) & 3;
  int ct = u >> 8;
  int n = ct * 16 + (ln & 15);
  int kb = kc * 32 + (ln >> 4) * 8;
  int head = n >> 5;
  const float* src = W + head * 4096 + (size_t)kb * 32 + (n & 31);
  unsigned hi[4], lo[4];
#pragma unroll
  for (int jj = 0; jj < 4; ++jj) {
    float w0 = src[(2 * jj) * 32];
    float w1 = src[(2 * jj + 1) * 32];
    unsigned h0 = f2bf(w0), h1 = f2bf(w1);
    unsigned l0 = f2bf(w0 - bf2f(h0)), l1 = f2bf(w1 - bf2f(h1));
    hi[jj] = h0 | (h1 << 16);
    lo[jj] = l0 | (l1 << 16);
  }
  gWf[u] = make_uint4(hi[0], hi[1], hi[2], hi[3]);
  gWf[2048 + u] = make_uint4(lo[0], lo[1], lo[2], lo[3]);
}

// ---------------- pure MFMA projection GEMM + attention dots ----------------
// Split-precision bf16 MFMA: X = Xh + Xl; A*B ~= Ah*Bh + Al*Bh + Ah*Bl.
__global__ __launch_bounds__(256) void k_gemm(const float* __restrict__ h,
                                              const uint4* __restrict__ gWf,
                                              const float* __restrict__ a,
                                              unsigned short* __restrict__ hp16,
                                              float* __restrict__ ssrc,
                                              float* __restrict__ sdst, int N) {
  __shared__ unsigned lds_u[16384];  // 64 KB: B-frags hi/lo; reused as epilogue buf
  const int tid = threadIdx.x;
  const int lane = tid & 63;
  const int wv = tid >> 6;
  const int quad = lane >> 4;
  const int l16 = lane & 15;

  for (int u = tid; u < 4096; u += 256)
    *(uint4*)&lds_u[u * 4] = gWf[u];

  const int row0 = blockIdx.x * 64;
  const int r = row0 + wv * 16 + l16;
  short8 Ah[4], Al[4];
#pragma unroll
  for (int kc = 0; kc < 4; ++kc) {
    float v[8];
    if (r < N) {
      float4 fa = *(const float4*)&h[(size_t)r * 128 + kc * 32 + quad * 8];
      float4 fb = *(const float4*)&h[(size_t)r * 128 + kc * 32 + quad * 8 + 4];
      v[0] = fa.x; v[1] = fa.y; v[2] = fa.z; v[3] = fa.w;
      v[4] = fb.x; v[5] = fb.y; v[6] = fb.z; v[7] = fb.w;
    } else {
#pragma unroll
      for (int j = 0; j < 8; ++j) v[j] = 0.f;
    }
#pragma unroll
    for (int j = 0; j < 8; ++j) {
      unsigned hi = f2bf(v[j]);
      Ah[kc][j] = (short)hi;
      Al[kc][j] = (short)f2bf(v[j] - bf2f(hi));
    }
  }
  __syncthreads();

  floatx4 C[8];
#pragma unroll
  for (int ct = 0; ct < 8; ++ct) {
    floatx4 c = {0.f, 0.f, 0.f, 0.f};
#pragma unroll
    for (int kc = 0; kc < 4; ++kc) {
      int bidx = ((ct * 4 + kc) * 64 + lane) * 4;
      short8 Bh, Bl;
      *(uint4*)&Bh = *(const uint4*)&lds_u[bidx];
      *(uint4*)&Bl = *(const uint4*)&lds_u[8192 + bidx];
      c = __builtin_amdgcn_mfma_f32_16x16x32_bf16(Ah[kc], Bh, c, 0, 0, 0);
      c = __builtin_amdgcn_mfma_f32_16x16x32_bf16(Al[kc], Bh, c, 0, 0, 0);
      c = __builtin_amdgcn_mfma_f32_16x16x32_bf16(Ah[kc], Bl, c, 0, 0, 0);
    }
    C[ct] = c;
  }
  __syncthreads();

  float* epi = (float*)lds_u;
#pragma unroll
  for (int ct = 0; ct < 8; ++ct) {
#pragma unroll
    for (int reg = 0; reg < 4; ++reg) {
      int rr = wv * 16 + quad * 4 + reg;
      epi[rr * 132 + ct * 16 + l16] = C[ct][reg];
    }
  }
  __syncthreads();

  const int row_l = tid >> 2;
  const int hh = tid & 3;
  const int rg = row0 + row_l;
  if (rg < N) {
    const float* rowp = &epi[row_l * 132 + hh * 32];
    float ss = 0.f, sd = 0.f;
    unsigned pka[16];
#pragma unroll
    for (int e = 0; e < 8; ++e) {
      float4 c4 = *(const float4*)&rowp[e * 4];
      float4 as = *(const float4*)&a[hh * 64 + e * 4];
      float4 ad = *(const float4*)&a[hh * 64 + 32 + e * 4];
      ss += c4.x * as.x + c4.y * as.y + c4.z * as.z + c4.w * as.w;
      sd += c4.x * ad.x + c4.y * ad.y + c4.z * ad.z + c4.w * ad.w;
      pka[e * 2] = f2bf(c4.x) | (f2bf(c4.y) << 16);
      pka[e * 2 + 1] = f2bf(c4.z) | (f2bf(c4.w) << 16);
    }
    unsigned short* dst = &hp16[(size_t)rg * 128 + hh * 32];
    *(uint4*)(dst) = make_uint4(pka[0], pka[1], pka[2], pka[3]);
    *(uint4*)(dst + 8) = make_uint4(pka[4], pka[5], pka[6], pka[7]);
    *(uint4*)(dst + 16) = make_uint4(pka[8], pka[9], pka[10], pka[11]);
    *(uint4*)(dst + 24) = make_uint4(pka[12], pka[13], pka[14], pka[15]);
    ssrc[(size_t)rg * 4 + hh] = ss;
    sdst[(size_t)rg * 4 + hh] = sd;
  }
}

// ---------------- bin edges into padded buckets (direct reservation) ----------------
// gpairs[bucket*BCAP + slot]; bucket cursor reserved per-(block,bucket) run via
// one returning atomicAdd (38K total, pipelined in L2); run writes contiguous.
__global__ __launch_bounds__(256) void k_bin(const int* __restrict__ ei,
                                             int* __restrict__ bcur,
                                             uint2* __restrict__ gpairs,
                                             int E, int NB2) {
  __shared__ uint2 stage[4096];  // 32 KB
  __shared__ int cnt[256], start[256], cur[256], gbase[256];
  __shared__ int lds[256];
  const int tid = threadIdx.x;
  const int e0 = blockIdx.x * 4096;
  for (int i = tid; i < NB2; i += 256) cnt[i] = 0;
  __syncthreads();
  int sarr[16], darr[16];
#pragma unroll
  for (int j = 0; j < 16; ++j) {
    int e = e0 + j * 256 + tid;
    if (e < E) {
      sarr[j] = ei[e];
      darr[j] = ei[E + e];
      atomicAdd(&cnt[darr[j] >> 8], 1);
    } else {
      darr[j] = -1;
    }
  }
  __syncthreads();
  {
    int s = (tid < NB2) ? cnt[tid] : 0;
    lds[tid] = s;
    __syncthreads();
    for (int off = 1; off < 256; off <<= 1) {
      int t = (tid >= off) ? lds[tid - off] : 0;
      __syncthreads();
      lds[tid] += t;
      __syncthreads();
    }
    if (tid < NB2) {
      start[tid] = lds[tid] - s;
      cur[tid] = lds[tid] - s;
      gbase[tid] = s ? atomicAdd(&bcur[tid], s) : 0;  // reserve run in bucket
    }
  }
  __syncthreads();
#pragma unroll
  for (int j = 0; j < 16; ++j) {
    if (darr[j] >= 0) {
      int b = darr[j] >> 8;
      int pos = atomicAdd(&cur[b], 1);
      stage[pos] = make_uint2((unsigned)sarr[j], (unsigned)darr[j]);
    }
  }
  __syncthreads();
  const int total = start[NB2 - 1] + cnt[NB2 - 1];
  for (int u = tid; u < total; u += 256) {
    uint2 pr = stage[u];
    int b = (int)(pr.y >> 8);
    gpairs[(size_t)b * BCAP + gbase[b] + (u - start[b])] = pr;
  }
}

// ---------------- per-bucket counting sort -> padded CSR + per-dst (beg,end) ----------------
__global__ __launch_bounds__(256) void k_build(const int* __restrict__ bcur,
                                               const uint2* __restrict__ gpairs,
                                               int* __restrict__ csr_src,
                                               int2* __restrict__ offs2, int N) {
  __shared__ int cnt2[256], start2[256], cur2[256];
  __shared__ int lds[256];
  __shared__ int srcsort[BCAP];  // 32 KB
  const int tid = threadIdx.x;
  const int b = blockIdx.x;
  const size_t base = (size_t)b * BCAP;
  const int size = bcur[b];
  const int d0 = b << 8;
  const int ndst = min(256, N - d0);
  cnt2[tid] = 0;
  __syncthreads();
  for (int u = tid; u < size; u += 256)
    atomicAdd(&cnt2[(int)gpairs[base + u].y - d0], 1);
  __syncthreads();
  {
    int s = cnt2[tid];
    lds[tid] = s;
    __syncthreads();
    for (int off = 1; off < 256; off <<= 1) {
      int t = (tid >= off) ? lds[tid - off] : 0;
      __syncthreads();
      lds[tid] += t;
      __syncthreads();
    }
    start2[tid] = lds[tid] - s;
    cur2[tid] = lds[tid] - s;
  }
  __syncthreads();
  for (int u = tid; u < size; u += 256) {
    uint2 pr = gpairs[base + u];
    int pos = atomicAdd(&cur2[(int)pr.y - d0], 1);
    srcsort[pos] = (int)pr.x;
  }
  __syncthreads();
  for (int u = tid; u < size; u += 256) csr_src[base + u] = srcsort[u];
  if (tid < ndst) {
    int beg = (int)base + start2[tid];
    offs2[d0 + tid] = make_int2(beg, beg + cnt2[tid]);
  }
}

// ---------------- aggregation: 16 lanes per dst, 8 ch/lane, unroll x4 ----------------
__global__ __launch_bounds__(256) void k_agg(const int2* __restrict__ offs2,
                                             const int* __restrict__ csr_src,
                                             const float* __restrict__ ssrc,
                                             const float* __restrict__ sdst,
                                             const uint4* __restrict__ hp4,
                                             float* __restrict__ out, int N) {
  const int t = blockIdx.x * 256 + threadIdx.x;
  const int d = t >> 4;
  if (d >= N) return;
  const int l = threadIdx.x & 15;
  const int hh = l >> 2;
  const int2 be = offs2[d];
  const int beg = be.x, end = be.y;
  const float sdh = sdst[(size_t)d * 4 + hh];

  float den[4] = {0.f, 0.f, 0.f, 0.f};
  float acc[8];
#pragma unroll
  for (int j = 0; j < 8; ++j) acc[j] = 0.f;

  int p = beg;
  for (; p + 3 < end; p += 4) {
    int s[4];
    float sc[4];
    uint4 v[4];
#pragma unroll
    for (int q = 0; q < 4; ++q) s[q] = csr_src[p + q];
#pragma unroll
    for (int q = 0; q < 4; ++q) {
      sc[q] = ssrc[(size_t)s[q] * 4 + hh] + sdh;
      v[q] = hp4[(size_t)s[q] * 16 + l];
    }
#pragma unroll
    for (int q = 0; q < 4; ++q) {
      float x = sc[q];
      x = x >= 0.f ? x : NEG_SLOPE * x;
      float w = __expf(x);
      den[q] += w;
      acc[0] = fmaf(w, bf2f(v[q].x & 0xffffu), acc[0]);
      acc[1] = fmaf(w, bf2f(v[q].x >> 16), acc[1]);
      acc[2] = fmaf(w, bf2f(v[q].y & 0xffffu), acc[2]);
      acc[3] = fmaf(w, bf2f(v[q].y >> 16), acc[3]);
      acc[4] = fmaf(w, bf2f(v[q].z & 0xffffu), acc[4]);
      acc[5] = fmaf(w, bf2f(v[q].z >> 16), acc[5]);
      acc[6] = fmaf(w, bf2f(v[q].w & 0xffffu), acc[6]);
      acc[7] = fmaf(w, bf2f(v[q].w >> 16), acc[7]);
    }
  }
  for (; p < end; ++p) {
    int s0 = csr_src[p];
    float sc0 = ssrc[(size_t)s0 * 4 + hh] + sdh;
    uint4 v0 = hp4[(size_t)s0 * 16 + l];
    sc0 = sc0 >= 0.f ? sc0 : NEG_SLOPE * sc0;
    float w0 = __expf(sc0);
    den[0] += w0;
    acc[0] = fmaf(w0, bf2f(v0.x & 0xffffu), acc[0]);
    acc[1] = fmaf(w0, bf2f(v0.x >> 16), acc[1]);
    acc[2] = fmaf(w0, bf2f(v0.y & 0xffffu), acc[2]);
    acc[3] = fmaf(w0, bf2f(v0.y >> 16), acc[3]);
    acc[4] = fmaf(w0, bf2f(v0.z & 0xffffu), acc[4]);
    acc[5] = fmaf(w0, bf2f(v0.z >> 16), acc[5]);
    acc[6] = fmaf(w0, bf2f(v0.w & 0xffffu), acc[6]);
    acc[7] = fmaf(w0, bf2f(v0.w >> 16), acc[7]);
  }
  float rden = 1.f / fmaxf((den[0] + den[1]) + (den[2] + den[3]), 1e-16f);
  float o[8];
#pragma unroll
  for (int j = 0; j < 8; ++j) {
    float x = acc[j] * rden;
    o[j] = x > 0.f ? x : expm1f(x);
  }
  float* dst = &out[(size_t)d * 128 + l * 8];
  *(float4*)dst = make_float4(o[0], o[1], o[2], o[3]);
  *(float4*)(dst + 4) = make_float4(o[4], o[5], o[6], o[7]);
}

extern "C" void kernel_launch(void* const* d_in, const int* in_sizes, int n_in,
                              void* d_out, int out_size, void* d_ws, size_t ws_size,
                              hipStream_t stream) {
  const float* h = (const float*)d_in[0];
  const int* ei = (const int*)d_in[1];
  const float* W = (const float*)d_in[2];
  const float* a = (const float*)d_in[3];
  float* out = (float*)d_out;
  const int N = in_sizes[0] / 128;
  const int E = in_sizes[1] / 2;
  const int NB2 = (N + 255) >> 8;          // coarse buckets (dst>>8), <=256
  const int NB1 = (E + 4095) / 4096;       // edge chunks

  char* ws = (char*)d_ws;
  uint4* gWf = (uint4*)ws;                                   // 4096 (64 KB)
  unsigned short* hp16 = (unsigned short*)(gWf + 4096);      // N*128 bf16
  uint2* gpairs = (uint2*)(hp16 + (size_t)N * 128);          // NB2*BCAP padded pairs
  int2* offs2 = (int2*)(gpairs + (size_t)NB2 * BCAP);        // N (beg,end)
  float* ssrc = (float*)(offs2 + N);                         // N*4
  float* sdst = ssrc + (size_t)N * 4;                        // N*4
  int* bcur = (int*)(sdst + (size_t)N * 4);                  // NB2
  int* csr_src = bcur + NB2;                                 // NB2*BCAP padded

  k_prep<<<8, 256, 0, stream>>>(W, gWf, bcur, NB2);
  k_gemm<<<(N + 63) / 64, 256, 0, stream>>>(h, gWf, a, hp16, ssrc, sdst, N);
  k_bin<<<NB1, 256, 0, stream>>>(ei, bcur, gpairs, E, NB2);
  k_build<<<NB2, 256, 0, stream>>>(bcur, gpairs, csr_src, offs2, N);
  k_agg<<<(N * 16 + 255) / 256, 256, 0, stream>>>(offs2, csr_src, ssrc, sdst,
                                                  (const uint4*)hp16, out, N);
}

// Round 13
// 159.282 us; speedup vs baseline: 1.4717x; 1.0024x over previous
//
#include <hip/hip_runtime.h>

#define NEG_SLOPE 0.2f
#define BCAP 8192  // per-bucket slot capacity (mean 4096, sigma ~64 -> +64 sigma)

typedef __attribute__((ext_vector_type(8))) short short8;
typedef __attribute__((ext_vector_type(4))) float floatx4;

__device__ __forceinline__ unsigned f2bf(float x) {
  unsigned u = __float_as_uint(x);
  unsigned r = ((u >> 16) & 1u) + 0x7fffu;
  return (u + r) >> 16;
}
__device__ __forceinline__ float bf2f(unsigned hi16) {
  return __uint_as_float(hi16 << 16);
}

// ---------------- one-shot: W -> MFMA B-fragments (hi/lo) + zero bucket cursors ----------------
__global__ __launch_bounds__(256) void k_prep(const float* __restrict__ W,
                                              uint4* __restrict__ gWf,
                                              int* __restrict__ bcur, int NB2) {
  if (blockIdx.x == 0 && threadIdx.x < NB2) bcur[threadIdx.x] = 0;
  const int u = blockIdx.x * 256 + threadIdx.x;
  if (u >= 2048) return;
  int ln = u & 63;
  int kc = (u >> 6) & 3;
  int ct = u >> 8;
  int n = ct * 16 + (ln & 15);
  int kb = kc * 32 + (ln >> 4) * 8;
  int head = n >> 5;
  const float* src = W + head * 4096 + (size_t)kb * 32 + (n & 31);
  unsigned hi[4], lo[4];
#pragma unroll
  for (int jj = 0; jj < 4; ++jj) {
    float w0 = src[(2 * jj) * 32];
    float w1 = src[(2 * jj + 1) * 32];
    unsigned h0 = f2bf(w0), h1 = f2bf(w1);
    unsigned l0 = f2bf(w0 - bf2f(h0)), l1 = f2bf(w1 - bf2f(h1));
    hi[jj] = h0 | (h1 << 16);
    lo[jj] = l0 | (l1 << 16);
  }
  gWf[u] = make_uint4(hi[0], hi[1], hi[2], hi[3]);
  gWf[2048 + u] = make_uint4(lo[0], lo[1], lo[2], lo[3]);
}

// ---------------- fused: edge binning + MFMA projection GEMM + attention dots ----------------
// First NB1 blocks bin their 4096-edge chunk into padded buckets, reusing the
// 64 KB lds_u as scratch BEFORE the gWf staging (block-sequential, no extra LDS).
__global__ __launch_bounds__(256) void k_gemm(const float* __restrict__ h,
                                              const uint4* __restrict__ gWf,
                                              const float* __restrict__ a,
                                              const int* __restrict__ ei,
                                              int* __restrict__ bcur,
                                              uint2* __restrict__ gpairs,
                                              unsigned short* __restrict__ hp16,
                                              float* __restrict__ ssrc,
                                              float* __restrict__ sdst,
                                              int N, int E, int NB1, int NB2) {
  __shared__ unsigned lds_u[16384];  // 64 KB multi-use: bin scratch -> B-frags -> epilogue
  const int tid = threadIdx.x;

  if (blockIdx.x < NB1) {  // block-uniform branch: barriers inside are legal
    uint2* stage = (uint2*)lds_u;              // 4096 pairs = 32 KB
    int* cnt = (int*)&lds_u[8192];
    int* start = (int*)&lds_u[8448];
    int* cur = (int*)&lds_u[8704];
    int* gbase = (int*)&lds_u[8960];
    int* scn = (int*)&lds_u[9216];
    const int e0 = blockIdx.x * 4096;
    for (int i = tid; i < NB2; i += 256) cnt[i] = 0;
    __syncthreads();
    int sarr[16], darr[16];
#pragma unroll
    for (int j = 0; j < 16; ++j) {
      int e = e0 + j * 256 + tid;
      if (e < E) {
        sarr[j] = ei[e];
        darr[j] = ei[E + e];
        atomicAdd(&cnt[darr[j] >> 8], 1);
      } else {
        darr[j] = -1;
      }
    }
    __syncthreads();
    int s = (tid < NB2) ? cnt[tid] : 0;
    scn[tid] = s;
    __syncthreads();
    for (int off = 1; off < 256; off <<= 1) {
      int t = (tid >= off) ? scn[tid - off] : 0;
      __syncthreads();
      scn[tid] += t;
      __syncthreads();
    }
    if (tid < NB2) {
      start[tid] = scn[tid] - s;
      cur[tid] = scn[tid] - s;
      gbase[tid] = s ? atomicAdd(&bcur[tid], s) : 0;  // reserve run in bucket
    }
    __syncthreads();
#pragma unroll
    for (int j = 0; j < 16; ++j) {
      if (darr[j] >= 0) {
        int b = darr[j] >> 8;
        int pos = atomicAdd(&cur[b], 1);
        stage[pos] = make_uint2((unsigned)sarr[j], (unsigned)darr[j]);
      }
    }
    __syncthreads();
    const int total = start[NB2 - 1] + cnt[NB2 - 1];
    for (int u = tid; u < total; u += 256) {
      uint2 pr = stage[u];
      int b = (int)(pr.y >> 8);
      gpairs[(size_t)b * BCAP + gbase[b] + (u - start[b])] = pr;
    }
    __syncthreads();  // lds_u scratch free
  }

  const int lane = tid & 63;
  const int wv = tid >> 6;
  const int quad = lane >> 4;
  const int l16 = lane & 15;

  for (int u = tid; u < 4096; u += 256)
    *(uint4*)&lds_u[u * 4] = gWf[u];

  const int row0 = blockIdx.x * 64;
  const int r = row0 + wv * 16 + l16;
  short8 Ah[4], Al[4];
#pragma unroll
  for (int kc = 0; kc < 4; ++kc) {
    float v[8];
    if (r < N) {
      float4 fa = *(const float4*)&h[(size_t)r * 128 + kc * 32 + quad * 8];
      float4 fb = *(const float4*)&h[(size_t)r * 128 + kc * 32 + quad * 8 + 4];
      v[0] = fa.x; v[1] = fa.y; v[2] = fa.z; v[3] = fa.w;
      v[4] = fb.x; v[5] = fb.y; v[6] = fb.z; v[7] = fb.w;
    } else {
#pragma unroll
      for (int j = 0; j < 8; ++j) v[j] = 0.f;
    }
#pragma unroll
    for (int j = 0; j < 8; ++j) {
      unsigned hi = f2bf(v[j]);
      Ah[kc][j] = (short)hi;
      Al[kc][j] = (short)f2bf(v[j] - bf2f(hi));
    }
  }
  __syncthreads();

  floatx4 C[8];
#pragma unroll
  for (int ct = 0; ct < 8; ++ct) {
    floatx4 c = {0.f, 0.f, 0.f, 0.f};
#pragma unroll
    for (int kc = 0; kc < 4; ++kc) {
      int bidx = ((ct * 4 + kc) * 64 + lane) * 4;
      short8 Bh, Bl;
      *(uint4*)&Bh = *(const uint4*)&lds_u[bidx];
      *(uint4*)&Bl = *(const uint4*)&lds_u[8192 + bidx];
      c = __builtin_amdgcn_mfma_f32_16x16x32_bf16(Ah[kc], Bh, c, 0, 0, 0);
      c = __builtin_amdgcn_mfma_f32_16x16x32_bf16(Al[kc], Bh, c, 0, 0, 0);
      c = __builtin_amdgcn_mfma_f32_16x16x32_bf16(Ah[kc], Bl, c, 0, 0, 0);
    }
    C[ct] = c;
  }
  __syncthreads();

  float* epi = (float*)lds_u;
#pragma unroll
  for (int ct = 0; ct < 8; ++ct) {
#pragma unroll
    for (int reg = 0; reg < 4; ++reg) {
      int rr = wv * 16 + quad * 4 + reg;
      epi[rr * 132 + ct * 16 + l16] = C[ct][reg];
    }
  }
  __syncthreads();

  const int row_l = tid >> 2;
  const int hh = tid & 3;
  const int rg = row0 + row_l;
  if (rg < N) {
    const float* rowp = &epi[row_l * 132 + hh * 32];
    float ss = 0.f, sd = 0.f;
    unsigned pka[16];
#pragma unroll
    for (int e = 0; e < 8; ++e) {
      float4 c4 = *(const float4*)&rowp[e * 4];
      float4 as = *(const float4*)&a[hh * 64 + e * 4];
      float4 ad = *(const float4*)&a[hh * 64 + 32 + e * 4];
      ss += c4.x * as.x + c4.y * as.y + c4.z * as.z + c4.w * as.w;
      sd += c4.x * ad.x + c4.y * ad.y + c4.z * ad.z + c4.w * ad.w;
      pka[e * 2] = f2bf(c4.x) | (f2bf(c4.y) << 16);
      pka[e * 2 + 1] = f2bf(c4.z) | (f2bf(c4.w) << 16);
    }
    unsigned short* dst = &hp16[(size_t)rg * 128 + hh * 32];
    *(uint4*)(dst) = make_uint4(pka[0], pka[1], pka[2], pka[3]);
    *(uint4*)(dst + 8) = make_uint4(pka[4], pka[5], pka[6], pka[7]);
    *(uint4*)(dst + 16) = make_uint4(pka[8], pka[9], pka[10], pka[11]);
    *(uint4*)(dst + 24) = make_uint4(pka[12], pka[13], pka[14], pka[15]);
    ssrc[(size_t)rg * 4 + hh] = ss;
    sdst[(size_t)rg * 4 + hh] = sd;
  }
}

// ---------------- per-bucket counting sort -> CSR + per-dst (beg,end) + edge weights ----------------
// During the scatter pass, compute w = exp(leaky_relu(ssrc[s]+sdst[d])) per head
// and store float4 per slot (escore): agg then needs NO score gather and NO exp.
__global__ __launch_bounds__(256) void k_build(const int* __restrict__ bcur,
                                               const uint2* __restrict__ gpairs,
                                               const float* __restrict__ ssrc,
                                               const float* __restrict__ sdst,
                                               int* __restrict__ csr_src,
                                               float4* __restrict__ escore,
                                               int2* __restrict__ offs2, int N) {
  __shared__ int cnt2[256], start2[256], cur2[256];
  __shared__ int lds[256];
  __shared__ int srcsort[BCAP];  // 32 KB
  const int tid = threadIdx.x;
  const int b = blockIdx.x;
  const size_t base = (size_t)b * BCAP;
  const int size = bcur[b];
  const int d0 = b << 8;
  const int ndst = min(256, N - d0);
  cnt2[tid] = 0;
  __syncthreads();
  for (int u = tid; u < size; u += 256)
    atomicAdd(&cnt2[(int)gpairs[base + u].y - d0], 1);
  __syncthreads();
  {
    int s = cnt2[tid];
    lds[tid] = s;
    __syncthreads();
    for (int off = 1; off < 256; off <<= 1) {
      int t = (tid >= off) ? lds[tid - off] : 0;
      __syncthreads();
      lds[tid] += t;
      __syncthreads();
    }
    start2[tid] = lds[tid] - s;
    cur2[tid] = lds[tid] - s;
  }
  __syncthreads();
  for (int u = tid; u < size; u += 256) {
    uint2 pr = gpairs[base + u];
    int d = (int)pr.y;
    int pos = atomicAdd(&cur2[d - d0], 1);
    int s = (int)pr.x;
    srcsort[pos] = s;
    float4 sv = *(const float4*)&ssrc[(size_t)s * 4];
    float4 dv = *(const float4*)&sdst[(size_t)d * 4];
    float4 w;
    float x;
    x = sv.x + dv.x; x = x >= 0.f ? x : NEG_SLOPE * x; w.x = __expf(x);
    x = sv.y + dv.y; x = x >= 0.f ? x : NEG_SLOPE * x; w.y = __expf(x);
    x = sv.z + dv.z; x = x >= 0.f ? x : NEG_SLOPE * x; w.z = __expf(x);
    x = sv.w + dv.w; x = x >= 0.f ? x : NEG_SLOPE * x; w.w = __expf(x);
    escore[base + pos] = w;
  }
  __syncthreads();
  for (int u = tid; u < size; u += 256) csr_src[base + u] = srcsort[u];
  if (tid < ndst) {
    int beg = (int)base + start2[tid];
    offs2[d0 + tid] = make_int2(beg, beg + cnt2[tid]);
  }
}

// ---------------- aggregation: 16 lanes per dst, 8 ch/lane, unroll x4 ----------------
// Weights precomputed (escore): only ONE random gather (hp) per edge, no exp.
__global__ __launch_bounds__(256) void k_agg(const int2* __restrict__ offs2,
                                             const int* __restrict__ csr_src,
                                             const float* __restrict__ escore,
                                             const uint4* __restrict__ hp4,
                                             float* __restrict__ out, int N) {
  const int t = blockIdx.x * 256 + threadIdx.x;
  const int d = t >> 4;
  if (d >= N) return;
  const int l = threadIdx.x & 15;
  const int hh = l >> 2;
  const int2 be = offs2[d];
  const int beg = be.x, end = be.y;

  float den[4] = {0.f, 0.f, 0.f, 0.f};
  float acc[8];
#pragma unroll
  for (int j = 0; j < 8; ++j) acc[j] = 0.f;

  int p = beg;
  for (; p + 3 < end; p += 4) {
    int s[4];
    float w[4];
    uint4 v[4];
#pragma unroll
    for (int q = 0; q < 4; ++q) s[q] = csr_src[p + q];
#pragma unroll
    for (int q = 0; q < 4; ++q) {
      w[q] = escore[(size_t)(p + q) * 4 + hh];
      v[q] = hp4[(size_t)s[q] * 16 + l];
    }
#pragma unroll
    for (int q = 0; q < 4; ++q) {
      den[q] += w[q];
      acc[0] = fmaf(w[q], bf2f(v[q].x & 0xffffu), acc[0]);
      acc[1] = fmaf(w[q], bf2f(v[q].x >> 16), acc[1]);
      acc[2] = fmaf(w[q], bf2f(v[q].y & 0xffffu), acc[2]);
      acc[3] = fmaf(w[q], bf2f(v[q].y >> 16), acc[3]);
      acc[4] = fmaf(w[q], bf2f(v[q].z & 0xffffu), acc[4]);
      acc[5] = fmaf(w[q], bf2f(v[q].z >> 16), acc[5]);
      acc[6] = fmaf(w[q], bf2f(v[q].w & 0xffffu), acc[6]);
      acc[7] = fmaf(w[q], bf2f(v[q].w >> 16), acc[7]);
    }
  }
  for (; p < end; ++p) {
    int s0 = csr_src[p];
    float w0 = escore[(size_t)p * 4 + hh];
    uint4 v0 = hp4[(size_t)s0 * 16 + l];
    den[0] += w0;
    acc[0] = fmaf(w0, bf2f(v0.x & 0xffffu), acc[0]);
    acc[1] = fmaf(w0, bf2f(v0.x >> 16), acc[1]);
    acc[2] = fmaf(w0, bf2f(v0.y & 0xffffu), acc[2]);
    acc[3] = fmaf(w0, bf2f(v0.y >> 16), acc[3]);
    acc[4] = fmaf(w0, bf2f(v0.z & 0xffffu), acc[4]);
    acc[5] = fmaf(w0, bf2f(v0.z >> 16), acc[5]);
    acc[6] = fmaf(w0, bf2f(v0.w & 0xffffu), acc[6]);
    acc[7] = fmaf(w0, bf2f(v0.w >> 16), acc[7]);
  }
  float rden = 1.f / fmaxf((den[0] + den[1]) + (den[2] + den[3]), 1e-16f);
  float o[8];
#pragma unroll
  for (int j = 0; j < 8; ++j) {
    float x = acc[j] * rden;
    o[j] = x > 0.f ? x : expm1f(x);
  }
  float* dst = &out[(size_t)d * 128 + l * 8];
  *(float4*)dst = make_float4(o[0], o[1], o[2], o[3]);
  *(float4*)(dst + 4) = make_float4(o[4], o[5], o[6], o[7]);
}

extern "C" void kernel_launch(void* const* d_in, const int* in_sizes, int n_in,
                              void* d_out, int out_size, void* d_ws, size_t ws_size,
                              hipStream_t stream) {
  const float* h = (const float*)d_in[0];
  const int* ei = (const int*)d_in[1];
  const float* W = (const float*)d_in[2];
  const float* a = (const float*)d_in[3];
  float* out = (float*)d_out;
  const int N = in_sizes[0] / 128;
  const int E = in_sizes[1] / 2;
  const int NB2 = (N + 255) >> 8;          // coarse buckets (dst>>8), <=256
  const int NB1 = (E + 4095) / 4096;       // edge chunks
  const int NBG = max((N + 63) / 64, NB1); // fused gemm+bin grid

  char* ws = (char*)d_ws;
  uint4* gWf = (uint4*)ws;                                   // 4096 (64 KB)
  unsigned short* hp16 = (unsigned short*)(gWf + 4096);      // N*128 bf16
  uint2* gpairs = (uint2*)(hp16 + (size_t)N * 128);          // NB2*BCAP padded pairs
  float4* escore = (float4*)(gpairs + (size_t)NB2 * BCAP);   // NB2*BCAP padded weights
  int2* offs2 = (int2*)(escore + (size_t)NB2 * BCAP);        // N (beg,end)
  float* ssrc = (float*)(offs2 + N);                         // N*4
  float* sdst = ssrc + (size_t)N * 4;                        // N*4
  int* bcur = (int*)(sdst + (size_t)N * 4);                  // NB2
  int* csr_src = bcur + NB2;                                 // NB2*BCAP padded

  k_prep<<<8, 256, 0, stream>>>(W, gWf, bcur, NB2);
  k_gemm<<<NBG, 256, 0, stream>>>(h, gWf, a, ei, bcur, gpairs, hp16, ssrc, sdst,
                                  N, E, NB1, NB2);
  k_build<<<NB2, 256, 0, stream>>>(bcur, gpairs, ssrc, sdst, csr_src, escore, offs2, N);
  k_agg<<<(N * 16 + 255) / 256, 256, 0, stream>>>(offs2, csr_src, (const float*)escore,
                                                  (const uint4*)hp16, out, N);
}